// Round 3
// baseline (1092.204 us; speedup 1.0000x reference)
//
#include <hip/hip_runtime.h>
#include <hip/hip_bf16.h>

typedef unsigned short u16;
typedef unsigned int u32;
typedef __attribute__((ext_vector_type(8))) short bf16x8;
typedef __attribute__((ext_vector_type(4))) float f32x4;
typedef __attribute__((ext_vector_type(4))) float float4v;

__device__ __forceinline__ float bf2f(u16 v) {
  union { u32 u; float f; } x; x.u = ((u32)v) << 16; return x.f;
}
__device__ __forceinline__ u16 f2bf(float f) {
  union { u32 u; float f; } x; x.f = f;
  return (u16)((x.u + 0x7fffu + ((x.u >> 16) & 1u)) >> 16);
}

__device__ __forceinline__ void gload16(const void* g, void* l) {
  __builtin_amdgcn_global_load_lds(
      (const __attribute__((address_space(1))) u32*)g,
      (__attribute__((address_space(3))) u32*)l, 16, 0, 0);
}

// ---------------- prep kernels ----------------

// fp32 -> bf16, 8 elements/thread (32B read, 16B write per lane)
__global__ void convert_bf16_kernel(const float* __restrict__ in,
                                    u16* __restrict__ out, int n8) {
  int t = blockIdx.x * blockDim.x + threadIdx.x;
  if (t >= n8) return;
  const float4v* p = (const float4v*)(in + (size_t)t * 8);
  float4v a = p[0], b = p[1];
  union { bf16x8 v; u16 s[8]; } o;
  o.s[0] = f2bf(a[0]); o.s[1] = f2bf(a[1]); o.s[2] = f2bf(a[2]); o.s[3] = f2bf(a[3]);
  o.s[4] = f2bf(b[0]); o.s[5] = f2bf(b[1]); o.s[6] = f2bf(b[2]); o.s[7] = f2bf(b[3]);
  *(bf16x8*)(out + (size_t)t * 8) = o.v;
}

// out[c*R + r] = bf16(in[r*C + c])  (fp32 -> bf16 transpose)
__global__ void transpose_kernel(const float* __restrict__ in, u16* __restrict__ out,
                                 int R, int C) {
  int t = blockIdx.x * blockDim.x + threadIdx.x;
  if (t >= R * C) return;
  int c = t / R, r = t % R;
  out[t] = f2bf(in[r * C + c]);
}

// CPB table MLP: tab[r][h] = sum_j hardswish(t0*w1[0][j]+t1*w1[1][j]) * w2[j][h]
__global__ void bias_tab_kernel(const float* __restrict__ w1, const float* __restrict__ w2,
                                float* __restrict__ tab) {
  int t = blockIdx.x * blockDim.x + threadIdx.x;
  if (t >= 225 * 16) return;
  int r = t >> 4, h = t & 15;
  int i = r / 15, j = r % 15;
  float gi = (float)(i - 7) * (8.0f / 7.0f);
  float gj = (float)(j - 7) * (8.0f / 7.0f);
  float si = (gi > 0.f) ? 1.f : ((gi < 0.f) ? -1.f : 0.f);
  float sj = (gj > 0.f) ? 1.f : ((gj < 0.f) ? -1.f : 0.f);
  float t0 = si * log2f(fabsf(gi) + 1.0f) * (1.0f / 3.0f);
  float t1 = sj * log2f(fabsf(gj) + 1.0f) * (1.0f / 3.0f);
  float acc = 0.f;
  for (int k = 0; k < 512; ++k) {
    float a = t0 * w1[k] + t1 * w1[512 + k];
    float hs = a * fminf(fmaxf(a + 3.f, 0.f), 6.f) * (1.f / 6.f);
    acc += hs * w2[k * 16 + h];
  }
  tab[t] = acc;
}

// bias16[h][n][m] = 16*sigmoid(tab[idx(n,m)][h])
__global__ void bias16_kernel(const float* __restrict__ tab, float* __restrict__ b16) {
  int t = blockIdx.x * blockDim.x + threadIdx.x;
  if (t >= 16 * 64 * 64) return;
  int h = t >> 12, nm = t & 4095, n = nm >> 6, m = nm & 63;
  int idx = ((n >> 3) - (m >> 3) + 7) * 15 + ((n & 7) - (m & 7) + 7);
  float b = tab[idx * 16 + h];
  b16[t] = 16.0f / (1.0f + expf(-b));
}

// ---------------- m97-style bf16 GEMM: C[M,N] = A[M,K] * Bt[N,K]^T ----------------
// F32OUT: store fp32 (final projection) vs bf16 (intermediates)
template <bool F32OUT>
__global__ __launch_bounds__(256) void gemm_bt(const u16* __restrict__ A,
                                               const u16* __restrict__ Bt,
                                               void* __restrict__ Cout,
                                               int M, int N, int K) {
  __shared__ u16 lA[128 * 64];
  __shared__ u16 lB[128 * 64];
  const int tid = threadIdx.x;
  const int w = tid >> 6, l = tid & 63;
  const int lg = l >> 4, li = l & 15;
  const int nbn = N >> 7;
  const int nwg = gridDim.x;
  int bidx = blockIdx.x;
  // bijective XCD-aware swizzle (m204 form), valid for any nwg
  int q = nwg >> 3, r = nwg & 7;
  int xcd = bidx & 7, pos = bidx >> 3;
  int swz = (xcd < r ? xcd * (q + 1) : r * (q + 1) + (xcd - r) * q) + pos;
  int bm = swz / nbn, bn = swz % nbn;
  const int wr = w >> 1, wc = w & 1;

  f32x4 acc[4][4];
#pragma unroll
  for (int i = 0; i < 4; i++)
#pragma unroll
    for (int j = 0; j < 4; j++) acc[i][j] = (f32x4){0.f, 0.f, 0.f, 0.f};

  const u16* Abase = A + (size_t)(bm * 128) * K;
  const u16* Bbase = Bt + (size_t)(bn * 128) * K;

  for (int k0 = 0; k0 < K; k0 += 64) {
#pragma unroll
    for (int i = 0; i < 4; ++i) {
      int c = w * 256 + i * 64 + l;  // 16B chunk id, 0..1023
      int row = c >> 3, kc = c & 7;
      gload16(Abase + (size_t)row * K + k0 + kc * 8, (u16*)lA + c * 8);
      gload16(Bbase + (size_t)row * K + k0 + kc * 8, (u16*)lB + c * 8);
    }
    __syncthreads();
#pragma unroll
    for (int kk = 0; kk < 2; ++kk) {
      bf16x8 af[4], bfr[4];
#pragma unroll
      for (int t = 0; t < 4; ++t) {
        int row = wr * 64 + t * 16 + li;
        af[t] = *(const bf16x8*)&lA[row * 64 + kk * 32 + lg * 8];
        int col = wc * 64 + t * 16 + li;
        bfr[t] = *(const bf16x8*)&lB[col * 64 + kk * 32 + lg * 8];
      }
#pragma unroll
      for (int tm = 0; tm < 4; ++tm)
#pragma unroll
        for (int tn = 0; tn < 4; ++tn)
          acc[tm][tn] = __builtin_amdgcn_mfma_f32_16x16x32_bf16(af[tm], bfr[tn],
                                                                acc[tm][tn], 0, 0, 0);
    }
    __syncthreads();
  }
  int r0 = bm * 128 + wr * 64 + lg * 4;
  int c0 = bn * 128 + wc * 64 + li;
#pragma unroll
  for (int tm = 0; tm < 4; ++tm)
#pragma unroll
    for (int tn = 0; tn < 4; ++tn)
#pragma unroll
      for (int j = 0; j < 4; ++j) {
        size_t off = (size_t)(r0 + tm * 16 + j) * N + c0 + tn * 16;
        if (F32OUT)
          ((float*)Cout)[off] = acc[tm][tn][j];
        else
          ((u16*)Cout)[off] = f2bf(acc[tm][tn][j]);
      }
}

// ---------------- attention: 1 block = 1 window, wave = head ----------------
// qkv: [wpc*64][1536] bf16 (q|k|v each h*32+d); softmax over HEADS per (n,m).
__global__ __launch_bounds__(1024) void attn_kernel(const u16* __restrict__ qkv,
                                                    const float* __restrict__ mask,
                                                    const float* __restrict__ bias16,
                                                    const float* __restrict__ lscale,
                                                    u16* __restrict__ aout,
                                                    int wbase) {
  __shared__ float S[16 * 32 * 65];  // [h][mloc][n] fp32, padded 65
  const int tid = threadIdx.x;
  const int h = tid >> 6;
  const int l = tid & 63;
  const int lg = l >> 4, li = l & 15;
  const int b = blockIdx.x;
  const int wm = (wbase + b) & 63;
  const u16* qb = qkv + (size_t)b * 64 * 1536;

  float sc = __expf(fminf(lscale[h], 4.6051702f));  // exp(min(ls, ln 100))

  // q fragments + row rnorms (broadcast via shfl; no LDS)
  bf16x8 qf[4];
  float rq[4];
#pragma unroll
  for (int tn = 0; tn < 4; ++tn) {
    int n = tn * 16 + li;
    qf[tn] = *(const bf16x8*)(qb + (size_t)n * 1536 + h * 32 + lg * 8);
    float ss = 0.f;
#pragma unroll
    for (int e = 0; e < 8; ++e) { float v = bf2f((u16)qf[tn][e]); ss += v * v; }
    ss += __shfl_xor(ss, 16);
    ss += __shfl_xor(ss, 32);
    rq[tn] = 1.0f / fmaxf(sqrtf(ss), 1e-12f);
  }
  float rqr[16];
#pragma unroll
  for (int tn = 0; tn < 4; ++tn)
#pragma unroll
    for (int j = 0; j < 4; ++j) rqr[tn * 4 + j] = __shfl(rq[tn], lg * 4 + j);

  f32x4 oacc[4][2];
#pragma unroll
  for (int i = 0; i < 4; i++) {
    oacc[i][0] = (f32x4){0.f, 0.f, 0.f, 0.f};
    oacc[i][1] = (f32x4){0.f, 0.f, 0.f, 0.f};
  }

  for (int c = 0; c < 2; ++c) {  // two 32-key chunks
    bf16x8 kf[2];
    float rk[2];
#pragma unroll
    for (int t = 0; t < 2; ++t) {
      int m = c * 32 + t * 16 + li;
      kf[t] = *(const bf16x8*)(qb + (size_t)m * 1536 + 512 + h * 32 + lg * 8);
      float ss = 0.f;
#pragma unroll
      for (int e = 0; e < 8; ++e) { float v = bf2f((u16)kf[t][e]); ss += v * v; }
      ss += __shfl_xor(ss, 16);
      ss += __shfl_xor(ss, 32);
      rk[t] = 1.0f / fmaxf(sqrtf(ss), 1e-12f);
    }
    // S = (q.k) * rq*rk*scale + bias + mask  -> LDS [h][mloc][n]
#pragma unroll
    for (int tn = 0; tn < 4; ++tn) {
#pragma unroll
      for (int t = 0; t < 2; ++t) {
        f32x4 z = {0.f, 0.f, 0.f, 0.f};
        f32x4 s = __builtin_amdgcn_mfma_f32_16x16x32_bf16(qf[tn], kf[t], z, 0, 0, 0);
        int mloc = t * 16 + li;
        int mg = c * 32 + mloc;
#pragma unroll
        for (int j = 0; j < 4; ++j) {
          int n = tn * 16 + lg * 4 + j;
          float v = s[j] * (rqr[tn * 4 + j] * rk[t] * sc) +
                    bias16[h * 4096 + n * 64 + mg] +
                    mask[wm * 4096 + n * 64 + mg];
          S[h * 2080 + mloc * 65 + n] = v;
        }
      }
    }
    __syncthreads();
    // softmax over the 16 heads, per (m,n); 2048 pairs / 1024 threads
#pragma unroll
    for (int pp = 0; pp < 2; ++pp) {
      int p = tid + pp * 1024;
      int base = (p >> 6) * 65 + (p & 63);
      float vals[16];
      float mx = -3.0e38f;
#pragma unroll
      for (int hh = 0; hh < 16; ++hh) {
        vals[hh] = S[hh * 2080 + base];
        mx = fmaxf(mx, vals[hh]);
      }
      float sum = 0.f;
#pragma unroll
      for (int hh = 0; hh < 16; ++hh) {
        float e = __expf(vals[hh] - mx);
        vals[hh] = e;
        sum += e;
      }
      float inv = 1.0f / sum;
#pragma unroll
      for (int hh = 0; hh < 16; ++hh) S[hh * 2080 + base] = vals[hh] * inv;
    }
    __syncthreads();
    // PV: P from LDS (own head slice), V direct from global
    bf16x8 pf[4];
#pragma unroll
    for (int tn = 0; tn < 4; ++tn) {
#pragma unroll
      for (int j = 0; j < 8; ++j) {
        int mloc = lg * 8 + j;
        pf[tn][j] = (short)f2bf(S[h * 2080 + mloc * 65 + tn * 16 + li]);
      }
    }
#pragma unroll
    for (int td = 0; td < 2; ++td) {
      bf16x8 vf;
#pragma unroll
      for (int j = 0; j < 8; ++j) {
        int m = c * 32 + lg * 8 + j;
        vf[j] = (short)qb[(size_t)m * 1536 + 1024 + h * 32 + td * 16 + li];
      }
#pragma unroll
      for (int tn = 0; tn < 4; ++tn)
        oacc[tn][td] = __builtin_amdgcn_mfma_f32_16x16x32_bf16(pf[tn], vf,
                                                               oacc[tn][td], 0, 0, 0);
    }
    __syncthreads();
  }
  // epilogue: attn_out[b*64+n][h*32+d]
#pragma unroll
  for (int tn = 0; tn < 4; ++tn)
#pragma unroll
    for (int td = 0; td < 2; ++td)
#pragma unroll
      for (int j = 0; j < 4; ++j) {
        int n = tn * 16 + lg * 4 + j;
        aout[((size_t)b * 64 + n) * 512 + h * 32 + td * 16 + li] = f2bf(oacc[tn][td][j]);
      }
}

extern "C" void kernel_launch(void* const* d_in, const int* in_sizes, int n_in,
                              void* d_out, int out_size, void* d_ws, size_t ws_size,
                              hipStream_t stream) {
  const float* x = (const float*)d_in[0];
  const float* mask = (const float*)d_in[1];
  const float* w_qkv = (const float*)d_in[2];
  const float* w_out = (const float*)d_in[3];
  const float* cpb_w1 = (const float*)d_in[4];
  const float* cpb_w2 = (const float*)d_in[5];
  const float* lscale = (const float*)d_in[6];
  float* out = (float*)d_out;

  // ---- workspace layout: small fixed buffers first, chunked big buffers after
  char* ws = (char*)d_ws;
  u16* wqkvT = (u16*)ws;                        // 1,572,864 B
  u16* woutT = (u16*)(ws + 1572864ull);         // 524,288 B
  float* btab = (float*)(ws + 2097152ull);      // 16,384 B
  float* b16 = (float*)(ws + 2113536ull);       // 262,144 B
  const size_t FIX = 2375680ull;
  // per window: x_bf16 (64x512x2) + qkv (64x1536x2) + attn_out (64x512x2)
  const size_t per_w = 65536ull + 196608ull + 65536ull;  // 327,680 B

  int wpc = 2048;  // windows per chunk (power of two), sized to fit ws
  while (wpc > 2 && FIX + (size_t)wpc * per_w > ws_size) wpc >>= 1;
  const int nch = 2048 / wpc;

  u16* xbf_ch = (u16*)(ws + FIX);
  u16* qkv_ch = xbf_ch + (size_t)wpc * 64 * 512;
  u16* attn_ch = qkv_ch + (size_t)wpc * 64 * 1536;

  // prep (once)
  transpose_kernel<<<(512 * 1536 + 255) / 256, 256, 0, stream>>>(w_qkv, wqkvT, 512, 1536);
  transpose_kernel<<<(512 * 512 + 255) / 256, 256, 0, stream>>>(w_out, woutT, 512, 512);
  bias_tab_kernel<<<(225 * 16 + 255) / 256, 256, 0, stream>>>(cpb_w1, cpb_w2, btab);
  bias16_kernel<<<(16 * 64 * 64 + 255) / 256, 256, 0, stream>>>(btab, b16);

  for (int ch = 0; ch < nch; ++ch) {
    const int M = wpc * 64;
    const size_t row0 = (size_t)ch * M;
    // x chunk -> bf16
    convert_bf16_kernel<<<(M * 64 + 255) / 256, 256, 0, stream>>>(
        x + row0 * 512, xbf_ch, M * 64);
    // qkv = x_chunk @ w_qkv   (M x 1536, K=512)
    gemm_bt<false><<<(M / 128) * 12, 256, 0, stream>>>(xbf_ch, wqkvT, qkv_ch,
                                                       M, 1536, 512);
    // attention per window
    attn_kernel<<<wpc, 1024, 0, stream>>>(qkv_ch, mask, b16, lscale, attn_ch,
                                          ch * wpc);
    // out_chunk = attn_chunk @ w_out  (M x 512, K=512), fp32 stores
    gemm_bt<true><<<(M / 128) * 4, 256, 0, stream>>>(attn_ch, woutT,
                                                     out + row0 * 512,
                                                     M, 512, 512);
  }
}